// Round 2
// baseline (5169.542 us; speedup 1.0000x reference)
//
#include <hip/hip_runtime.h>
#include <math.h>

typedef __bf16 bf16;
typedef __bf16 bf16x8 __attribute__((ext_vector_type(8)));
typedef float f32x4 __attribute__((ext_vector_type(4)));

constexpr int cT = 2048;
constexpr int cD = 4096;
constexpr int cH = 32;
constexpr int cKV = 8;
constexpr int cHD = 128;
constexpr float SCALE = 0.08838834764831845f; // 1/sqrt(128)

// Load 8 contiguous elements as bf16x8, converting from fp32 if needed.
__device__ inline bf16x8 load8_cvt(const float* __restrict__ p) {
  float4 a = *(const float4*)p;
  float4 b = *(const float4*)(p + 4);
  bf16x8 r;
  r[0] = (bf16)a.x; r[1] = (bf16)a.y; r[2] = (bf16)a.z; r[3] = (bf16)a.w;
  r[4] = (bf16)b.x; r[5] = (bf16)b.y; r[6] = (bf16)b.z; r[7] = (bf16)b.w;
  return r;
}
__device__ inline bf16x8 load8_cvt(const bf16* __restrict__ p) {
  return *(const bf16x8*)p;
}

// ---------------------------------------------------------------------------
// GEMM: C[M,N] = A[M,K] @ B[K,N], bf16 MFMA, fp32 accum.
// A/B may be fp32 (converted to bf16 at LDS staging) or bf16.
// 64x64 block tile, 256 threads (4 waves), each wave 32x32 (2x2 MFMA tiles).
// MFMA 16x16x32 bf16 layouts (HW-verified per guide):
//   A-frag: A[m=lane&15][k=(lane>>4)*8+j]
//   B-frag: B[k=(lane>>4)*8+j][n=lane&15]
//   C/D:    col=lane&15, row=(lane>>4)*4+reg
// ---------------------------------------------------------------------------
template <typename AT, typename BT, typename OutT>
__global__ __launch_bounds__(256) void gemm_kernel(const AT* __restrict__ A,
                                                   const BT* __restrict__ B,
                                                   OutT* __restrict__ C,
                                                   int M, int N, int K) {
  __shared__ bf16 As[64][32];
  __shared__ bf16 Bs[32][64];
  const int tid = threadIdx.x;
  const int m0 = blockIdx.y * 64;
  const int n0 = blockIdx.x * 64;
  const int lane = tid & 63;
  const int wave = tid >> 6;
  const int wm = (wave >> 1) * 32;
  const int wn = (wave & 1) * 32;
  const int ln = lane & 15;
  const int kg = lane >> 4;  // 0..3

  f32x4 acc[2][2] = {};

  // staging: each thread loads one 8-element chunk of A and one of B per K-tile
  const int ar = tid >> 2, ac = (tid & 3) * 8;  // A: 64 rows x 32 cols
  const int br = tid >> 3, bc = (tid & 7) * 8;  // B: 32 rows x 64 cols
  const AT* aptr = A + (size_t)(m0 + ar) * K + ac;
  const BT* bptr = B + (size_t)br * N + n0 + bc;

  for (int kt = 0; kt < K; kt += 32) {
    *(bf16x8*)(&As[ar][ac]) = load8_cvt(aptr + kt);
    *(bf16x8*)(&Bs[br][bc]) = load8_cvt(bptr + (size_t)kt * N);
    __syncthreads();

    bf16x8 af[2], bfr[2];
#pragma unroll
    for (int tm = 0; tm < 2; ++tm)
      af[tm] = *(const bf16x8*)(&As[wm + tm * 16 + ln][kg * 8]);
#pragma unroll
    for (int tn = 0; tn < 2; ++tn) {
#pragma unroll
      for (int j = 0; j < 8; ++j)
        bfr[tn][j] = Bs[kg * 8 + j][wn + tn * 16 + ln];
    }
#pragma unroll
    for (int tm = 0; tm < 2; ++tm)
#pragma unroll
      for (int tn = 0; tn < 2; ++tn)
        acc[tm][tn] = __builtin_amdgcn_mfma_f32_16x16x32_bf16(
            af[tm], bfr[tn], acc[tm][tn], 0, 0, 0);
    __syncthreads();
  }

#pragma unroll
  for (int tm = 0; tm < 2; ++tm)
#pragma unroll
    for (int tn = 0; tn < 2; ++tn)
#pragma unroll
      for (int r = 0; r < 4; ++r) {
        int row = m0 + wm + tm * 16 + kg * 4 + r;
        int col = n0 + wn + tn * 16 + ln;
        C[(size_t)row * N + col] = (OutT)acc[tm][tn][r];
      }
}

// ---------------------------------------------------------------------------
// RMSNorm (per head, HD=128) + RoPE, in place on fp32 q and k.
// One wave per (t, head). Lane holds dims d0=2*lane, d0+1.
// rotate_half partner (dim d ^ 64) lives in lane^32.
// ---------------------------------------------------------------------------
__global__ __launch_bounds__(256) void norm_rope_kernel(float* __restrict__ q,
                                                        float* __restrict__ k,
                                                        const float* __restrict__ qw,
                                                        const float* __restrict__ kw) {
  const int gw = (blockIdx.x * 256 + threadIdx.x) >> 6;
  const int lane = threadIdx.x & 63;
  float* base;
  const float* wgt;
  int t;
  if (gw < cT * cH) {
    t = gw / cH;
    int h = gw % cH;
    base = q + ((size_t)t * cH + h) * cHD;
    wgt = qw;
  } else {
    int g2 = gw - cT * cH;
    t = g2 / cKV;
    int h = g2 % cKV;
    base = k + ((size_t)t * cKV + h) * cHD;
    wgt = kw;
  }
  const int d0 = lane * 2;
  float2 x = *(float2*)(base + d0);
  float ss = x.x * x.x + x.y * x.y;
#pragma unroll
  for (int off = 32; off > 0; off >>= 1) ss += __shfl_xor(ss, off, 64);
  const float rs = rsqrtf(ss * (1.0f / 128.0f) + 1e-6f);
  float y0 = x.x * rs * wgt[d0];
  float y1 = x.y * rs * wgt[d0 + 1];
  float p0 = __shfl_xor(y0, 32, 64);
  float p1 = __shfl_xor(y1, 32, 64);
  const float sgn = (lane < 32) ? -1.0f : 1.0f;  // first half gets -x2
  const int fi = d0 & 63;
  const float c1 = -19.93156856932417f / 64.0f;  // -log2(1e6)/64
  float inv0 = exp2f((float)fi * c1);
  float inv1 = exp2f((float)(fi + 1) * c1);
  float a0 = (float)t * inv0, a1 = (float)t * inv1;
  float o0 = y0 * cosf(a0) + sgn * p0 * sinf(a0);
  float o1 = y1 * cosf(a1) + sgn * p1 * sinf(a1);
  *(float2*)(base + d0) = make_float2(o0, o1);
}

// ---------------------------------------------------------------------------
// Causal GQA attention, online softmax. One wave per (t, h).
// q,k,v fp32; out bf16 in (t, h, d) layout == (T, H*HD) row-major.
// ---------------------------------------------------------------------------
__global__ __launch_bounds__(256) void attn_kernel(const float* __restrict__ q,
                                                   const float* __restrict__ k,
                                                   const float* __restrict__ v,
                                                   bf16* __restrict__ out) {
  const int gw = (blockIdx.x * 256 + threadIdx.x) >> 6;
  const int lane = threadIdx.x & 63;
  const int h = gw % cH;  // waves in a block share t -> balanced loop lengths
  const int t = gw / cH;
  const int kh = h >> 2;  // G = 4
  const float2 qv = *(const float2*)(q + ((size_t)t * cH + h) * cHD + lane * 2);
  const float q0 = qv.x * SCALE, q1 = qv.y * SCALE;
  const float* kp = k + (size_t)kh * cHD + lane * 2;
  const float* vp = v + (size_t)kh * cHD + lane * 2;
  float m = -INFINITY, l = 0.0f, o0 = 0.0f, o1 = 0.0f;
  for (int s = 0; s <= t; ++s) {
    float2 kv2 = *(const float2*)kp;
    float d = q0 * kv2.x + q1 * kv2.y;
#pragma unroll
    for (int off = 32; off > 0; off >>= 1) d += __shfl_xor(d, off, 64);
    float mn = fmaxf(m, d);
    float al = __expf(m - mn);  // m=-inf first iter -> al=0
    float p = __expf(d - mn);
    float2 vv = *(const float2*)vp;
    l = l * al + p;
    o0 = o0 * al + p * vv.x;
    o1 = o1 * al + p * vv.y;
    m = mn;
    kp += cKV * cHD;
    vp += cKV * cHD;
  }
  const float il = 1.0f / l;
  bf16* op = out + ((size_t)t * cH + h) * cHD + lane * 2;
  op[0] = (bf16)(o0 * il);
  op[1] = (bf16)(o1 * il);
}

// ---------------------------------------------------------------------------
extern "C" void kernel_launch(void* const* d_in, const int* in_sizes, int n_in,
                              void* d_out, int out_size, void* d_ws, size_t ws_size,
                              hipStream_t stream) {
  const float* x  = (const float*)d_in[0];
  const float* Wq = (const float*)d_in[1];
  const float* Wk = (const float*)d_in[2];
  const float* Wv = (const float*)d_in[3];
  const float* Wo = (const float*)d_in[4];
  const float* qw = (const float*)d_in[5];
  const float* kw = (const float*)d_in[6];
  float* out = (float*)d_out;

  char* ws = (char*)d_ws;
  float* q = (float*)ws;                    // 2048*4096*4 = 32 MB
  float* k = (float*)(ws + 33554432);       //  8 MB
  float* v = (float*)(ws + 41943040);       //  8 MB
  bf16* attn = (bf16*)(ws + 50331648);      // 16 MB  (total 64 MB)

  // q/k/v projections (fp32 inputs -> bf16 MFMA -> fp32 out)
  gemm_kernel<float, float, float><<<dim3(cD / 64, cT / 64), 256, 0, stream>>>(
      x, Wq, q, cT, cD, cD);
  gemm_kernel<float, float, float><<<dim3((cKV * cHD) / 64, cT / 64), 256, 0, stream>>>(
      x, Wk, k, cT, cKV * cHD, cD);
  gemm_kernel<float, float, float><<<dim3((cKV * cHD) / 64, cT / 64), 256, 0, stream>>>(
      x, Wv, v, cT, cKV * cHD, cD);

  // rmsnorm + rope on q and k (in place)
  const int nr_waves = cT * (cH + cKV);
  norm_rope_kernel<<<nr_waves / 4, 256, 0, stream>>>(q, k, qw, kw);

  // causal GQA attention -> bf16 (T, H*HD)
  attn_kernel<<<(cT * cH) / 4, 256, 0, stream>>>(q, k, v, attn);

  // output projection -> d_out (fp32)
  gemm_kernel<bf16, float, float><<<dim3(cD / 64, cT / 64), 256, 0, stream>>>(
      attn, Wo, out, cT, cD, cD);
}

// Round 3
// 1107.336 us; speedup vs baseline: 4.6684x; 4.6684x over previous
//
#include <hip/hip_runtime.h>
#include <math.h>

typedef __bf16 bf16;
typedef __bf16 bf16x8 __attribute__((ext_vector_type(8)));
typedef float f32x4 __attribute__((ext_vector_type(4)));

constexpr int cT = 2048;
constexpr int cD = 4096;
constexpr int cH = 32;
constexpr int cKV = 8;
constexpr int cHD = 128;
constexpr float SCALE = 0.08838834764831845f; // 1/sqrt(128)

// Load 8 contiguous elements as bf16x8, converting from fp32 if needed.
__device__ inline bf16x8 load8_cvt(const float* __restrict__ p) {
  float4 a = *(const float4*)p;
  float4 b = *(const float4*)(p + 4);
  bf16x8 r;
  r[0] = (bf16)a.x; r[1] = (bf16)a.y; r[2] = (bf16)a.z; r[3] = (bf16)a.w;
  r[4] = (bf16)b.x; r[5] = (bf16)b.y; r[6] = (bf16)b.z; r[7] = (bf16)b.w;
  return r;
}
__device__ inline bf16x8 load8_cvt(const bf16* __restrict__ p) {
  return *(const bf16x8*)p;
}

// ---------------------------------------------------------------------------
// GEMM: C[M,N] = A[M,K] @ B[K,N], bf16 MFMA, fp32 accum. (unchanged this round)
// ---------------------------------------------------------------------------
template <typename AT, typename BT, typename OutT>
__global__ __launch_bounds__(256) void gemm_kernel(const AT* __restrict__ A,
                                                   const BT* __restrict__ B,
                                                   OutT* __restrict__ C,
                                                   int M, int N, int K) {
  __shared__ bf16 As[64][32];
  __shared__ bf16 Bs[32][64];
  const int tid = threadIdx.x;
  const int m0 = blockIdx.y * 64;
  const int n0 = blockIdx.x * 64;
  const int lane = tid & 63;
  const int wave = tid >> 6;
  const int wm = (wave >> 1) * 32;
  const int wn = (wave & 1) * 32;
  const int ln = lane & 15;
  const int kg = lane >> 4;  // 0..3

  f32x4 acc[2][2] = {};

  const int ar = tid >> 2, ac = (tid & 3) * 8;  // A: 64 rows x 32 cols
  const int br = tid >> 3, bc = (tid & 7) * 8;  // B: 32 rows x 64 cols
  const AT* aptr = A + (size_t)(m0 + ar) * K + ac;
  const BT* bptr = B + (size_t)br * N + n0 + bc;

  for (int kt = 0; kt < K; kt += 32) {
    *(bf16x8*)(&As[ar][ac]) = load8_cvt(aptr + kt);
    *(bf16x8*)(&Bs[br][bc]) = load8_cvt(bptr + (size_t)kt * N);
    __syncthreads();

    bf16x8 af[2], bfr[2];
#pragma unroll
    for (int tm = 0; tm < 2; ++tm)
      af[tm] = *(const bf16x8*)(&As[wm + tm * 16 + ln][kg * 8]);
#pragma unroll
    for (int tn = 0; tn < 2; ++tn) {
#pragma unroll
      for (int j = 0; j < 8; ++j)
        bfr[tn][j] = Bs[kg * 8 + j][wn + tn * 16 + ln];
    }
#pragma unroll
    for (int tm = 0; tm < 2; ++tm)
#pragma unroll
      for (int tn = 0; tn < 2; ++tn)
        acc[tm][tn] = __builtin_amdgcn_mfma_f32_16x16x32_bf16(
            af[tm], bfr[tn], acc[tm][tn], 0, 0, 0);
    __syncthreads();
  }

#pragma unroll
  for (int tm = 0; tm < 2; ++tm)
#pragma unroll
    for (int tn = 0; tn < 2; ++tn)
#pragma unroll
      for (int r = 0; r < 4; ++r) {
        int row = m0 + wm + tm * 16 + kg * 4 + r;
        int col = n0 + wn + tn * 16 + ln;
        C[(size_t)row * N + col] = (OutT)acc[tm][tn][r];
      }
}

// ---------------------------------------------------------------------------
// RMSNorm (per head, HD=128) + RoPE, in place on fp32 q and k.
// Q additionally pre-scaled by 1/sqrt(HD) (folded softmax scale).
// ---------------------------------------------------------------------------
__global__ __launch_bounds__(256) void norm_rope_kernel(float* __restrict__ q,
                                                        float* __restrict__ k,
                                                        const float* __restrict__ qw,
                                                        const float* __restrict__ kw) {
  const int gw = (blockIdx.x * 256 + threadIdx.x) >> 6;
  const int lane = threadIdx.x & 63;
  float* base;
  const float* wgt;
  float post;
  int t;
  if (gw < cT * cH) {
    t = gw / cH;
    int h = gw % cH;
    base = q + ((size_t)t * cH + h) * cHD;
    wgt = qw;
    post = SCALE;
  } else {
    int g2 = gw - cT * cH;
    t = g2 / cKV;
    int h = g2 % cKV;
    base = k + ((size_t)t * cKV + h) * cHD;
    wgt = kw;
    post = 1.0f;
  }
  const int d0 = lane * 2;
  float2 x = *(float2*)(base + d0);
  float ss = x.x * x.x + x.y * x.y;
#pragma unroll
  for (int off = 32; off > 0; off >>= 1) ss += __shfl_xor(ss, off, 64);
  const float rs = rsqrtf(ss * (1.0f / 128.0f) + 1e-6f);
  float y0 = x.x * rs * wgt[d0];
  float y1 = x.y * rs * wgt[d0 + 1];
  float p0 = __shfl_xor(y0, 32, 64);
  float p1 = __shfl_xor(y1, 32, 64);
  const float sgn = (lane < 32) ? -1.0f : 1.0f;  // first half gets -x2
  const int fi = d0 & 63;
  const float c1 = -19.93156856932417f / 64.0f;  // -log2(1e6)/64
  float inv0 = exp2f((float)fi * c1);
  float inv1 = exp2f((float)(fi + 1) * c1);
  float a0 = (float)t * inv0, a1 = (float)t * inv1;
  float o0 = (y0 * cosf(a0) + sgn * p0 * sinf(a0)) * post;
  float o1 = (y1 * cosf(a1) + sgn * p1 * sinf(a1)) * post;
  *(float2*)(base + d0) = make_float2(o0, o1);
}

// ---------------------------------------------------------------------------
// MFMA flash attention (causal, GQA). One workgroup per (64-row Q-tile, head).
// 4 waves; wave w owns Q-rows [qm0+16w, qm0+16w+16).
// K staged bf16 in LDS [64][136]; V staged TRANSPOSED [128][72] (pair-packed
// b32 writes, conflict-free); P round-trips through wave-private LDS strip
// to convert C-layout -> A-layout (guide m120 pattern).
// MFMA 16x16x32 layouts (HW-verified):
//   A-frag: A[m=lane&15][k=(lane>>4)*8+j]
//   B-frag: B[k=(lane>>4)*8+j][n=lane&15]
//   C/D:    col=lane&15, row=(lane>>4)*4+reg
// ---------------------------------------------------------------------------
__global__ __launch_bounds__(256) void flash_kernel(const float* __restrict__ q,
                                                    const float* __restrict__ k,
                                                    const float* __restrict__ v,
                                                    bf16* __restrict__ out) {
  __shared__ bf16 Ks[64][136];
  __shared__ bf16 VT[128][72];
  __shared__ bf16 Ps[4][16][72];

  const int qt = blockIdx.x;   // q-tile index, rows [64qt, 64qt+64)
  const int h = blockIdx.y;    // q head
  const int qm0 = qt * 64;
  const int kh = h >> 2;       // kv head (G=4)
  const int tid = threadIdx.x;
  const int lane = tid & 63, w = tid >> 6;
  const int ln = lane & 15, kg = lane >> 4;

  // --- preload Q A-frags (q already scaled by 1/sqrt(HD) in norm_rope) ---
  bf16x8 qa[4];
  {
    const float* qrow =
        q + (size_t)(qm0 + w * 16 + ln) * (cH * cHD) + (size_t)h * cHD + kg * 8;
#pragma unroll
    for (int kk = 0; kk < 4; ++kk) qa[kk] = load8_cvt(qrow + kk * 32);
  }

  // --- staging index precompute ---
  const int sl = tid >> 2, sc = tid & 3;       // K: row sl, dim chunk sc*32
  const int vp = tid & 31, vc = tid >> 5;      // V: row-pair 2*vp, dim chunk vc*16

  float m_r[4] = {-1e30f, -1e30f, -1e30f, -1e30f};
  float l_r[4] = {0.f, 0.f, 0.f, 0.f};
  f32x4 o_acc[8] = {};

  for (int kt = 0; kt <= qt; ++kt) {
    // ---- stage K tile: Ks[s][d] = bf16(k[kt*64+s][kh][d]) ----
    {
      const float* krow =
          k + (size_t)(kt * 64 + sl) * (cKV * cHD) + (size_t)kh * cHD + sc * 32;
#pragma unroll
      for (int i = 0; i < 4; ++i)
        *(bf16x8*)(&Ks[sl][sc * 32 + i * 8]) = load8_cvt(krow + i * 8);
    }
    // ---- stage V tile transposed: VT[d][s] = bf16(v[kt*64+s][kh][d]) ----
    {
      const float* v0 =
          v + (size_t)(kt * 64 + 2 * vp) * (cKV * cHD) + (size_t)kh * cHD + vc * 16;
#pragma unroll
      for (int j = 0; j < 16; j += 4) {
        float4 a = *(const float4*)(v0 + j);
        float4 b = *(const float4*)(v0 + cKV * cHD + j);
        const float* ap = &a.x;
        const float* bp = &b.x;
#pragma unroll
        for (int i = 0; i < 4; ++i) {
          union { bf16 hh[2]; unsigned u; } pk;
          pk.hh[0] = (bf16)ap[i];
          pk.hh[1] = (bf16)bp[i];
          *(unsigned*)(&VT[vc * 16 + j + i][2 * vp]) = pk.u;
        }
      }
    }
    __syncthreads();

    // ---- S = Q K^T (16x16x32 MFMA), strip 16 x 64 ----
    f32x4 s_acc[4] = {};
#pragma unroll
    for (int nt = 0; nt < 4; ++nt) {
#pragma unroll
      for (int kk = 0; kk < 4; ++kk) {
        bf16x8 bfr = *(const bf16x8*)(&Ks[nt * 16 + ln][kk * 32 + kg * 8]);
        s_acc[nt] = __builtin_amdgcn_mfma_f32_16x16x32_bf16(qa[kk], bfr,
                                                            s_acc[nt], 0, 0, 0);
      }
    }

    // ---- causal mask (diagonal tile only) ----
    if (kt == qt) {
      const int qrow_loc = w * 16 + kg * 4;  // + r
#pragma unroll
      for (int nt = 0; nt < 4; ++nt)
#pragma unroll
        for (int r = 0; r < 4; ++r)
          if (nt * 16 + ln > qrow_loc + r) s_acc[nt][r] = -1e30f;
    }

    // ---- online softmax: row max ----
    float mx[4];
#pragma unroll
    for (int r = 0; r < 4; ++r) {
      float v0 = fmaxf(fmaxf(s_acc[0][r], s_acc[1][r]),
                       fmaxf(s_acc[2][r], s_acc[3][r]));
#pragma unroll
      for (int off = 8; off > 0; off >>= 1) v0 = fmaxf(v0, __shfl_xor(v0, off, 64));
      mx[r] = v0;
    }
    float al[4];
#pragma unroll
    for (int r = 0; r < 4; ++r) {
      float mn = fmaxf(m_r[r], mx[r]);
      al[r] = __expf(m_r[r] - mn);
      m_r[r] = mn;
    }
    // ---- P = exp(S - m), row sums, write P strip to LDS ----
    float rs[4] = {0.f, 0.f, 0.f, 0.f};
#pragma unroll
    for (int nt = 0; nt < 4; ++nt)
#pragma unroll
      for (int r = 0; r < 4; ++r) {
        float p = __expf(s_acc[nt][r] - m_r[r]);
        s_acc[nt][r] = p;
        rs[r] += p;
      }
#pragma unroll
    for (int r = 0; r < 4; ++r) {
#pragma unroll
      for (int off = 8; off > 0; off >>= 1) rs[r] += __shfl_xor(rs[r], off, 64);
      l_r[r] = l_r[r] * al[r] + rs[r];
    }
#pragma unroll
    for (int nt = 0; nt < 4; ++nt)
#pragma unroll
      for (int r = 0; r < 4; ++r)
        Ps[w][kg * 4 + r][nt * 16 + ln] = (bf16)s_acc[nt][r];

    // ---- rescale O by alpha (rows match: C-row = kg*4+r) ----
#pragma unroll
    for (int dt = 0; dt < 8; ++dt)
#pragma unroll
      for (int r = 0; r < 4; ++r) o_acc[dt][r] *= al[r];

    // ---- O += P V  (A-frags from wave-private Ps strip; B from VT) ----
#pragma unroll
    for (int kk2 = 0; kk2 < 2; ++kk2) {
      bf16x8 pa = *(const bf16x8*)(&Ps[w][ln][kk2 * 32 + kg * 8]);
#pragma unroll
      for (int dt = 0; dt < 8; ++dt) {
        bf16x8 vb = *(const bf16x8*)(&VT[dt * 16 + ln][kk2 * 32 + kg * 8]);
        o_acc[dt] = __builtin_amdgcn_mfma_f32_16x16x32_bf16(pa, vb, o_acc[dt],
                                                            0, 0, 0);
      }
    }
    __syncthreads();  // protect Ks/VT before next tile's staging
  }

  // ---- epilogue: O /= l, store bf16 (t, h, d) ----
  float il[4];
#pragma unroll
  for (int r = 0; r < 4; ++r) il[r] = 1.0f / l_r[r];
  bf16* op = out + (size_t)(qm0 + w * 16 + kg * 4) * (cH * cHD) +
             (size_t)h * cHD + ln;
#pragma unroll
  for (int dt = 0; dt < 8; ++dt)
#pragma unroll
    for (int r = 0; r < 4; ++r)
      op[(size_t)r * (cH * cHD) + dt * 16] = (bf16)(o_acc[dt][r] * il[r]);
}

// ---------------------------------------------------------------------------
extern "C" void kernel_launch(void* const* d_in, const int* in_sizes, int n_in,
                              void* d_out, int out_size, void* d_ws, size_t ws_size,
                              hipStream_t stream) {
  const float* x  = (const float*)d_in[0];
  const float* Wq = (const float*)d_in[1];
  const float* Wk = (const float*)d_in[2];
  const float* Wv = (const float*)d_in[3];
  const float* Wo = (const float*)d_in[4];
  const float* qw = (const float*)d_in[5];
  const float* kw = (const float*)d_in[6];
  float* out = (float*)d_out;

  char* ws = (char*)d_ws;
  float* q = (float*)ws;                    // 2048*4096*4 = 32 MB
  float* k = (float*)(ws + 33554432);       //  8 MB
  float* v = (float*)(ws + 41943040);       //  8 MB
  bf16* attn = (bf16*)(ws + 50331648);      // 16 MB  (total 64 MB)

  // q/k/v projections (fp32 inputs -> bf16 MFMA -> fp32 out)
  gemm_kernel<float, float, float><<<dim3(cD / 64, cT / 64), 256, 0, stream>>>(
      x, Wq, q, cT, cD, cD);
  gemm_kernel<float, float, float><<<dim3((cKV * cHD) / 64, cT / 64), 256, 0, stream>>>(
      x, Wk, k, cT, cKV * cHD, cD);
  gemm_kernel<float, float, float><<<dim3((cKV * cHD) / 64, cT / 64), 256, 0, stream>>>(
      x, Wv, v, cT, cKV * cHD, cD);

  // rmsnorm + rope on q and k (in place; q pre-scaled by 1/sqrt(HD))
  const int nr_waves = cT * (cH + cKV);
  norm_rope_kernel<<<nr_waves / 4, 256, 0, stream>>>(q, k, qw, kw);

  // flash attention -> bf16 (T, H*HD)
  flash_kernel<<<dim3(cT / 64, cH), 256, 0, stream>>>(q, k, v, attn);

  // output projection -> d_out (fp32)
  gemm_kernel<bf16, float, float><<<dim3(cD / 64, cT / 64), 256, 0, stream>>>(
      attn, Wo, out, cT, cD, cD);
}

// Round 4
// 687.056 us; speedup vs baseline: 7.5242x; 1.6117x over previous
//
#include <hip/hip_runtime.h>
#include <math.h>

typedef __bf16 bf16;
typedef __bf16 bf16x8 __attribute__((ext_vector_type(8)));
typedef float f32x4 __attribute__((ext_vector_type(4)));

constexpr int cT = 2048;
constexpr int cD = 4096;
constexpr int cH = 32;
constexpr int cKV = 8;
constexpr int cHD = 128;
constexpr float SCALE = 0.08838834764831845f; // 1/sqrt(128)

// Async global->LDS, 16B per lane. LDS dest must be WAVE-UNIFORM base;
// lane i's data lands at base + i*16 (guide §5 caveat).
__device__ __forceinline__ void gl_lds16(const bf16* g, bf16* l) {
  __builtin_amdgcn_global_load_lds(
      (const __attribute__((address_space(1))) unsigned*)g,
      (__attribute__((address_space(3))) unsigned*)l, 16, 0, 0);
}

__device__ inline bf16x8 load8_cvt(const float* __restrict__ p) {
  float4 a = *(const float4*)p;
  float4 b = *(const float4*)(p + 4);
  bf16x8 r;
  r[0] = (bf16)a.x; r[1] = (bf16)a.y; r[2] = (bf16)a.z; r[3] = (bf16)a.w;
  r[4] = (bf16)b.x; r[5] = (bf16)b.y; r[6] = (bf16)b.z; r[7] = (bf16)b.w;
  return r;
}

// ---------------------------------------------------------------------------
// fp32 -> bf16 elementwise (8 elems/thread)
// ---------------------------------------------------------------------------
__global__ __launch_bounds__(256) void convert_kernel(const float* __restrict__ s,
                                                      bf16* __restrict__ d) {
  const size_t i = (size_t)(blockIdx.x * 256 + threadIdx.x) * 8;
  *(bf16x8*)(d + i) = load8_cvt(s + i);
}

// ---------------------------------------------------------------------------
// Transpose + convert: dst[c][r] = (bf16)src[r][c]. src is R x C fp32,
// dst is C x R bf16 (row stride R). 64x64 LDS tile.
// ---------------------------------------------------------------------------
__global__ __launch_bounds__(256) void convT_kernel(const float* __restrict__ src,
                                                    bf16* __restrict__ dst,
                                                    int R, int C) {
  __shared__ float t[64][65];
  const int r0 = blockIdx.y * 64, c0 = blockIdx.x * 64;
  const int tid = threadIdx.x;
  {
    const int lr = tid >> 4, lc = (tid & 15) * 4;
#pragma unroll
    for (int i = 0; i < 4; ++i) {
      float4 v4 = *(const float4*)(src + (size_t)(r0 + lr + i * 16) * C + c0 + lc);
      t[lr + i * 16][lc] = v4.x;
      t[lr + i * 16][lc + 1] = v4.y;
      t[lr + i * 16][lc + 2] = v4.z;
      t[lr + i * 16][lc + 3] = v4.w;
    }
  }
  __syncthreads();
  {
    const int c = tid >> 2, rb = (tid & 3) * 16;
#pragma unroll
    for (int half = 0; half < 2; ++half) {
      bf16x8 o;
#pragma unroll
      for (int j = 0; j < 8; ++j) o[j] = (bf16)t[rb + half * 8 + j][c];
      *(bf16x8*)(dst + (size_t)(c0 + c) * R + r0 + rb + half * 8) = o;
    }
  }
}

// ---------------------------------------------------------------------------
// m97-structure GEMM: C[M,N] = A[M,K] * BT[N,K]^T, both operands bf16
// K-major. 128xBN block tile, BK=32, 256 threads (4 waves, 2x2), each wave
// 64 x BN/2 (4 x BN/32 MFMA 16x16x32 tiles). Both A and B staged via
// global_load_lds width=16; all fragment reads ds_read_b128.
//   A-frag: A[m=lane&15][k=(lane>>4)*8+j]
//   B-frag: B[k=(lane>>4)*8+j][n=lane&15]  (= BT[n][k], contiguous k)
//   C/D:    col=lane&15, row=(lane>>4)*4+reg
// ---------------------------------------------------------------------------
template <int BN, typename OutT>
__global__ __launch_bounds__(256) void gemm_bt_kernel(const bf16* __restrict__ A,
                                                      const bf16* __restrict__ BT,
                                                      OutT* __restrict__ C,
                                                      int M, int N, int K) {
  __shared__ __align__(16) bf16 As[128][32];
  __shared__ __align__(16) bf16 Bs[BN][32];
  constexpr int TN = BN / 32;  // n-tiles per wave

  const int tid = threadIdx.x;
  const int lane = tid & 63, w = tid >> 6;
  const int ln = lane & 15, kg = lane >> 4;
  const int m0 = blockIdx.y * 128, n0 = blockIdx.x * BN;
  const int wm = (w >> 1) * 64;
  const int wn = (w & 1) * (BN / 2);

  f32x4 acc[4][TN] = {};

  const int srow = lane >> 2;          // 0..15 within a 16-row chunk
  const int schk = (lane & 3) * 8;     // k-chunk (bf16 elems)
  const bf16* aG = A + (size_t)(m0 + srow) * K + schk;
  const bf16* bG = BT + (size_t)(n0 + srow) * K + schk;

  for (int kt = 0; kt < K; kt += 32) {
#pragma unroll
    for (int j = 0; j < 2; ++j)
      gl_lds16(aG + (size_t)(w * 32 + j * 16) * K + kt, &As[w * 32 + j * 16][0]);
#pragma unroll
    for (int j = 0; j < BN / 64; ++j)
      gl_lds16(bG + (size_t)(w * (BN / 4) + j * 16) * K + kt,
               &Bs[w * (BN / 4) + j * 16][0]);
    __syncthreads();

    bf16x8 af[4], bfr[TN];
#pragma unroll
    for (int tm = 0; tm < 4; ++tm)
      af[tm] = *(const bf16x8*)(&As[wm + tm * 16 + ln][kg * 8]);
#pragma unroll
    for (int tn = 0; tn < TN; ++tn)
      bfr[tn] = *(const bf16x8*)(&Bs[wn + tn * 16 + ln][kg * 8]);
#pragma unroll
    for (int tm = 0; tm < 4; ++tm)
#pragma unroll
      for (int tn = 0; tn < TN; ++tn)
        acc[tm][tn] = __builtin_amdgcn_mfma_f32_16x16x32_bf16(
            af[tm], bfr[tn], acc[tm][tn], 0, 0, 0);
    __syncthreads();
  }

#pragma unroll
  for (int tm = 0; tm < 4; ++tm)
#pragma unroll
    for (int tn = 0; tn < TN; ++tn)
#pragma unroll
      for (int r = 0; r < 4; ++r)
        C[(size_t)(m0 + wm + tm * 16 + kg * 4 + r) * N + n0 + wn + tn * 16 + ln] =
            (OutT)acc[tm][tn][r];
}

// ---------------------------------------------------------------------------
// RMSNorm (per head, HD=128) + RoPE, in place on bf16 q and kv(k part).
// Q additionally pre-scaled by 1/sqrt(HD). One wave per (t, head).
// ---------------------------------------------------------------------------
__global__ __launch_bounds__(256) void norm_rope_kernel(bf16* __restrict__ q,
                                                        bf16* __restrict__ kv,
                                                        const float* __restrict__ qw,
                                                        const float* __restrict__ kw) {
  const int gw = (blockIdx.x * 256 + threadIdx.x) >> 6;
  const int lane = threadIdx.x & 63;
  bf16* base;
  const float* wgt;
  float post;
  int t;
  if (gw < cT * cH) {
    t = gw >> 5;
    int h = gw & 31;
    base = q + (size_t)t * (cH * cHD) + h * cHD;
    wgt = qw;
    post = SCALE;
  } else {
    int g2 = gw - cT * cH;
    t = g2 >> 3;
    int h = g2 & 7;
    base = kv + (size_t)t * (2 * cKV * cHD) + h * cHD;  // k part of kv buffer
    wgt = kw;
    post = 1.0f;
  }
  const int d0 = lane * 2;
  float x0 = (float)base[d0], x1 = (float)base[d0 + 1];
  float ss = x0 * x0 + x1 * x1;
#pragma unroll
  for (int off = 32; off > 0; off >>= 1) ss += __shfl_xor(ss, off, 64);
  const float rs = rsqrtf(ss * (1.0f / 128.0f) + 1e-6f);
  float y0 = x0 * rs * wgt[d0];
  float y1 = x1 * rs * wgt[d0 + 1];
  float p0 = __shfl_xor(y0, 32, 64);
  float p1 = __shfl_xor(y1, 32, 64);
  const float sgn = (lane < 32) ? -1.0f : 1.0f;  // first half gets -x2
  const int fi = d0 & 63;
  const float c1 = -19.93156856932417f / 64.0f;  // -log2(1e6)/64
  float inv0 = exp2f((float)fi * c1);
  float inv1 = exp2f((float)(fi + 1) * c1);
  float a0 = (float)t * inv0, a1 = (float)t * inv1;
  float o0 = (y0 * cosf(a0) + sgn * p0 * sinf(a0)) * post;
  float o1 = (y1 * cosf(a1) + sgn * p1 * sinf(a1)) * post;
  base[d0] = (bf16)o0;
  base[d0 + 1] = (bf16)o1;
}

// ---------------------------------------------------------------------------
// MFMA flash attention (causal, GQA), bf16 inputs.
// q: [T][H*HD] bf16 (pre-scaled). kv: [T][2*KV*HD] bf16, k = cols 0..1023,
// v = cols 1024..2047. One workgroup per (64-row Q-tile, head); 4 waves,
// wave w owns rows [qm0+16w, +16).
// ---------------------------------------------------------------------------
__global__ __launch_bounds__(256) void flash_kernel(const bf16* __restrict__ q,
                                                    const bf16* __restrict__ kv,
                                                    bf16* __restrict__ out) {
  __shared__ bf16 Ks[64][136];
  __shared__ bf16 VT[128][72];
  __shared__ bf16 Ps[4][16][72];

  constexpr int KVS = 2 * cKV * cHD;  // 2048, kv row stride
  const int qt = blockIdx.x;
  const int h = blockIdx.y;
  const int qm0 = qt * 64;
  const int kh = h >> 2;  // kv head (G=4)
  const int tid = threadIdx.x;
  const int lane = tid & 63, w = tid >> 6;
  const int ln = lane & 15, kg = lane >> 4;

  // --- preload Q A-frags ---
  bf16x8 qa[4];
  {
    const bf16* qrow =
        q + (size_t)(qm0 + w * 16 + ln) * (cH * cHD) + h * cHD + kg * 8;
#pragma unroll
    for (int kk = 0; kk < 4; ++kk) qa[kk] = *(const bf16x8*)(qrow + kk * 32);
  }

  const int sl = tid >> 2, sc = tid & 3;    // K staging: row sl, chunk sc*32
  const int vp = tid & 31, vc = tid >> 5;   // V staging: row-pair 2vp, chunk vc*16

  float m_r[4] = {-1e30f, -1e30f, -1e30f, -1e30f};
  float l_r[4] = {0.f, 0.f, 0.f, 0.f};
  f32x4 o_acc[8] = {};

  for (int kt = 0; kt <= qt; ++kt) {
    // ---- stage K tile ----
    {
      const bf16* krow = kv + (size_t)(kt * 64 + sl) * KVS + kh * cHD + sc * 32;
#pragma unroll
      for (int i = 0; i < 4; ++i)
        *(bf16x8*)(&Ks[sl][sc * 32 + i * 8]) = *(const bf16x8*)(krow + i * 8);
    }
    // ---- stage V tile transposed (pair-packed b32 writes) ----
    {
      const bf16* vrow =
          kv + cKV * cHD + (size_t)(kt * 64 + 2 * vp) * KVS + kh * cHD + vc * 16;
      bf16x8 a0 = *(const bf16x8*)(vrow);
      bf16x8 a1 = *(const bf16x8*)(vrow + 8);
      bf16x8 b0 = *(const bf16x8*)(vrow + KVS);
      bf16x8 b1 = *(const bf16x8*)(vrow + KVS + 8);
#pragma unroll
      for (int i = 0; i < 8; ++i) {
        union { bf16 hh[2]; unsigned u; } pk;
        pk.hh[0] = a0[i]; pk.hh[1] = b0[i];
        *(unsigned*)(&VT[vc * 16 + i][2 * vp]) = pk.u;
        pk.hh[0] = a1[i]; pk.hh[1] = b1[i];
        *(unsigned*)(&VT[vc * 16 + 8 + i][2 * vp]) = pk.u;
      }
    }
    __syncthreads();

    // ---- S = Q K^T ----
    f32x4 s_acc[4] = {};
#pragma unroll
    for (int nt = 0; nt < 4; ++nt) {
#pragma unroll
      for (int kk = 0; kk < 4; ++kk) {
        bf16x8 bfr = *(const bf16x8*)(&Ks[nt * 16 + ln][kk * 32 + kg * 8]);
        s_acc[nt] = __builtin_amdgcn_mfma_f32_16x16x32_bf16(qa[kk], bfr,
                                                            s_acc[nt], 0, 0, 0);
      }
    }

    // ---- causal mask (diagonal tile only) ----
    if (kt == qt) {
      const int qrow_loc = w * 16 + kg * 4;
#pragma unroll
      for (int nt = 0; nt < 4; ++nt)
#pragma unroll
        for (int r = 0; r < 4; ++r)
          if (nt * 16 + ln > qrow_loc + r) s_acc[nt][r] = -1e30f;
    }

    // ---- online softmax ----
    float mx[4];
#pragma unroll
    for (int r = 0; r < 4; ++r) {
      float v0 = fmaxf(fmaxf(s_acc[0][r], s_acc[1][r]),
                       fmaxf(s_acc[2][r], s_acc[3][r]));
#pragma unroll
      for (int off = 8; off > 0; off >>= 1) v0 = fmaxf(v0, __shfl_xor(v0, off, 64));
      mx[r] = v0;
    }
    float al[4];
#pragma unroll
    for (int r = 0; r < 4; ++r) {
      float mn = fmaxf(m_r[r], mx[r]);
      al[r] = __expf(m_r[r] - mn);
      m_r[r] = mn;
    }
    float rs[4] = {0.f, 0.f, 0.f, 0.f};
#pragma unroll
    for (int nt = 0; nt < 4; ++nt)
#pragma unroll
      for (int r = 0; r < 4; ++r) {
        float p = __expf(s_acc[nt][r] - m_r[r]);
        s_acc[nt][r] = p;
        rs[r] += p;
      }
#pragma unroll
    for (int r = 0; r < 4; ++r) {
#pragma unroll
      for (int off = 8; off > 0; off >>= 1) rs[r] += __shfl_xor(rs[r], off, 64);
      l_r[r] = l_r[r] * al[r] + rs[r];
    }
#pragma unroll
    for (int nt = 0; nt < 4; ++nt)
#pragma unroll
      for (int r = 0; r < 4; ++r)
        Ps[w][kg * 4 + r][nt * 16 + ln] = (bf16)s_acc[nt][r];

#pragma unroll
    for (int dt = 0; dt < 8; ++dt)
#pragma unroll
      for (int r = 0; r < 4; ++r) o_acc[dt][r] *= al[r];

    // ---- O += P V ----
#pragma unroll
    for (int kk2 = 0; kk2 < 2; ++kk2) {
      bf16x8 pa = *(const bf16x8*)(&Ps[w][ln][kk2 * 32 + kg * 8]);
#pragma unroll
      for (int dt = 0; dt < 8; ++dt) {
        bf16x8 vb = *(const bf16x8*)(&VT[dt * 16 + ln][kk2 * 32 + kg * 8]);
        o_acc[dt] = __builtin_amdgcn_mfma_f32_16x16x32_bf16(pa, vb, o_acc[dt],
                                                            0, 0, 0);
      }
    }
    __syncthreads();
  }

  // ---- epilogue ----
  float il[4];
#pragma unroll
  for (int r = 0; r < 4; ++r) il[r] = 1.0f / l_r[r];
  bf16* op = out + (size_t)(qm0 + w * 16 + kg * 4) * (cH * cHD) + h * cHD + ln;
#pragma unroll
  for (int dt = 0; dt < 8; ++dt)
#pragma unroll
    for (int r = 0; r < 4; ++r)
      op[(size_t)r * (cH * cHD) + dt * 16] = (bf16)(o_acc[dt][r] * il[r]);
}

// ---------------------------------------------------------------------------
// Workspace choreography (peak exactly 64 MiB, stream-ordered reuse):
//   [ 0,16M): xb (x bf16)            -> attn (after kv-gemm done)
//   [16,48M): WqT (32M)              -> { WkvT [16,32M), kv [32,40M) } -> WoT
//   [48,64M): q bf16
// ---------------------------------------------------------------------------
extern "C" void kernel_launch(void* const* d_in, const int* in_sizes, int n_in,
                              void* d_out, int out_size, void* d_ws, size_t ws_size,
                              hipStream_t stream) {
  const float* x  = (const float*)d_in[0];
  const float* Wq = (const float*)d_in[1];
  const float* Wk = (const float*)d_in[2];
  const float* Wv = (const float*)d_in[3];
  const float* Wo = (const float*)d_in[4];
  const float* qw = (const float*)d_in[5];
  const float* kw = (const float*)d_in[6];
  float* out = (float*)d_out;

  char* ws = (char*)d_ws;
  bf16* xb   = (bf16*)ws;
  bf16* WqT  = (bf16*)(ws + (16u << 20));
  bf16* WkvT = (bf16*)(ws + (16u << 20));
  bf16* kvb  = (bf16*)(ws + (32u << 20));
  bf16* qb   = (bf16*)(ws + (48u << 20));
  bf16* attn = (bf16*)ws;
  bf16* WoT  = (bf16*)(ws + (16u << 20));

  // x -> bf16
  convert_kernel<<<(cT * cD) / (8 * 256), 256, 0, stream>>>(x, xb);
  // Wq^T bf16; q = xb * WqT^T (bf16 out)
  convT_kernel<<<dim3(cD / 64, cD / 64), 256, 0, stream>>>(Wq, WqT, cD, cD);
  gemm_bt_kernel<128, bf16><<<dim3(cD / 128, cT / 128), 256, 0, stream>>>(
      xb, WqT, qb, cT, cD, cD);
  // Wk^T|Wv^T bf16 (fused 2048x4096); kv = xb * WkvT^T (bf16 out)
  convT_kernel<<<dim3((cKV * cHD) / 64, cD / 64), 256, 0, stream>>>(Wk, WkvT, cD, cKV * cHD);
  convT_kernel<<<dim3((cKV * cHD) / 64, cD / 64), 256, 0, stream>>>(
      Wv, WkvT + (size_t)(cKV * cHD) * cD, cD, cKV * cHD);
  gemm_bt_kernel<64, bf16><<<dim3((2 * cKV * cHD) / 64, cT / 128), 256, 0, stream>>>(
      xb, WkvT, kvb, cT, 2 * cKV * cHD, cD);
  // rmsnorm + rope (in place, bf16)
  norm_rope_kernel<<<(cT * (cH + cKV)) / 4, 256, 0, stream>>>(qb, kvb, qw, kw);
  // flash attention -> attn bf16 (reuses xb region)
  flash_kernel<<<dim3(cT / 64, cH), 256, 0, stream>>>(qb, kvb, attn);
  // Wo^T bf16 (overwrites WkvT/kv region - both dead); out = attn * WoT^T (fp32)
  convT_kernel<<<dim3(cD / 64, cD / 64), 256, 0, stream>>>(Wo, WoT, cD, cD);
  gemm_bt_kernel<128, float><<<dim3(cD / 128, cT / 128), 256, 0, stream>>>(
      attn, WoT, out, cT, cD, cD);
}

// Round 5
// 633.428 us; speedup vs baseline: 8.1612x; 1.0847x over previous
//
#include <hip/hip_runtime.h>
#include <math.h>

typedef __bf16 bf16;
typedef __bf16 bf16x8 __attribute__((ext_vector_type(8)));
typedef float f32x4 __attribute__((ext_vector_type(4)));

constexpr int cT = 2048;
constexpr int cD = 4096;
constexpr int cH = 32;
constexpr int cKV = 8;
constexpr int cHD = 128;
constexpr float SCALE = 0.08838834764831845f; // 1/sqrt(128)

// Async global->LDS, 16B per lane. LDS dest must be WAVE-UNIFORM base;
// lane i's data lands at base + i*16 (guide §5 caveat).
__device__ __forceinline__ void gl_lds16(const bf16* g, bf16* l) {
  __builtin_amdgcn_global_load_lds(
      (const __attribute__((address_space(1))) unsigned*)g,
      (__attribute__((address_space(3))) unsigned*)l, 16, 0, 0);
}

__device__ inline bf16x8 load8_cvt(const float* __restrict__ p) {
  float4 a = *(const float4*)p;
  float4 b = *(const float4*)(p + 4);
  bf16x8 r;
  r[0] = (bf16)a.x; r[1] = (bf16)a.y; r[2] = (bf16)a.z; r[3] = (bf16)a.w;
  r[4] = (bf16)b.x; r[5] = (bf16)b.y; r[6] = (bf16)b.z; r[7] = (bf16)b.w;
  return r;
}

// ---------------------------------------------------------------------------
// fp32 -> bf16 elementwise (8 elems/thread)
// ---------------------------------------------------------------------------
__global__ __launch_bounds__(256) void convert_kernel(const float* __restrict__ s,
                                                      bf16* __restrict__ d) {
  const size_t i = (size_t)(blockIdx.x * 256 + threadIdx.x) * 8;
  *(bf16x8*)(d + i) = load8_cvt(s + i);
}

// ---------------------------------------------------------------------------
// Transpose + convert: dst[c][r] = (bf16)src[r][c]. src is R x C fp32,
// dst is C x R bf16 (row stride R). 64x64 LDS tile.
// ---------------------------------------------------------------------------
__global__ __launch_bounds__(256) void convT_kernel(const float* __restrict__ src,
                                                    bf16* __restrict__ dst,
                                                    int R, int C) {
  __shared__ float t[64][65];
  const int r0 = blockIdx.y * 64, c0 = blockIdx.x * 64;
  const int tid = threadIdx.x;
  {
    const int lr = tid >> 4, lc = (tid & 15) * 4;
#pragma unroll
    for (int i = 0; i < 4; ++i) {
      float4 v4 = *(const float4*)(src + (size_t)(r0 + lr + i * 16) * C + c0 + lc);
      t[lr + i * 16][lc] = v4.x;
      t[lr + i * 16][lc + 1] = v4.y;
      t[lr + i * 16][lc + 2] = v4.z;
      t[lr + i * 16][lc + 3] = v4.w;
    }
  }
  __syncthreads();
  {
    const int c = tid >> 2, rb = (tid & 3) * 16;
#pragma unroll
    for (int half = 0; half < 2; ++half) {
      bf16x8 o;
#pragma unroll
      for (int j = 0; j < 8; ++j) o[j] = (bf16)t[rb + half * 8 + j][c];
      *(bf16x8*)(dst + (size_t)(c0 + c) * R + r0 + rb + half * 8) = o;
    }
  }
}

// ---------------------------------------------------------------------------
// m97-structure GEMM: C[M,N] = A[M,K] * BT[N,K]^T, both operands bf16
// K-major. 128xBN block tile, BK=32, 256 threads (4 waves, 2x2).
// ---------------------------------------------------------------------------
template <int BN, typename OutT>
__global__ __launch_bounds__(256) void gemm_bt_kernel(const bf16* __restrict__ A,
                                                      const bf16* __restrict__ BT,
                                                      OutT* __restrict__ C,
                                                      int M, int N, int K) {
  __shared__ __align__(16) bf16 As[128][32];
  __shared__ __align__(16) bf16 Bs[BN][32];
  constexpr int TN = BN / 32;  // n-tiles per wave

  const int tid = threadIdx.x;
  const int lane = tid & 63, w = tid >> 6;
  const int ln = lane & 15, kg = lane >> 4;
  const int m0 = blockIdx.y * 128, n0 = blockIdx.x * BN;
  const int wm = (w >> 1) * 64;
  const int wn = (w & 1) * (BN / 2);

  f32x4 acc[4][TN] = {};

  const int srow = lane >> 2;          // 0..15 within a 16-row chunk
  const int schk = (lane & 3) * 8;     // k-chunk (bf16 elems)
  const bf16* aG = A + (size_t)(m0 + srow) * K + schk;
  const bf16* bG = BT + (size_t)(n0 + srow) * K + schk;

  for (int kt = 0; kt < K; kt += 32) {
#pragma unroll
    for (int j = 0; j < 2; ++j)
      gl_lds16(aG + (size_t)(w * 32 + j * 16) * K + kt, &As[w * 32 + j * 16][0]);
#pragma unroll
    for (int j = 0; j < BN / 64; ++j)
      gl_lds16(bG + (size_t)(w * (BN / 4) + j * 16) * K + kt,
               &Bs[w * (BN / 4) + j * 16][0]);
    __syncthreads();

    bf16x8 af[4], bfr[TN];
#pragma unroll
    for (int tm = 0; tm < 4; ++tm)
      af[tm] = *(const bf16x8*)(&As[wm + tm * 16 + ln][kg * 8]);
#pragma unroll
    for (int tn = 0; tn < TN; ++tn)
      bfr[tn] = *(const bf16x8*)(&Bs[wn + tn * 16 + ln][kg * 8]);
#pragma unroll
    for (int tm = 0; tm < 4; ++tm)
#pragma unroll
      for (int tn = 0; tn < TN; ++tn)
        acc[tm][tn] = __builtin_amdgcn_mfma_f32_16x16x32_bf16(
            af[tm], bfr[tn], acc[tm][tn], 0, 0, 0);
    __syncthreads();
  }

#pragma unroll
  for (int tm = 0; tm < 4; ++tm)
#pragma unroll
    for (int tn = 0; tn < TN; ++tn)
#pragma unroll
      for (int r = 0; r < 4; ++r)
        C[(size_t)(m0 + wm + tm * 16 + kg * 4 + r) * N + n0 + wn + tn * 16 + ln] =
            (OutT)acc[tm][tn][r];
}

// ---------------------------------------------------------------------------
// RMSNorm (per head, HD=128) + RoPE, in place on bf16 q and kv(k part).
// Q additionally pre-scaled by 1/sqrt(HD). One wave per (t, head).
// ---------------------------------------------------------------------------
__global__ __launch_bounds__(256) void norm_rope_kernel(bf16* __restrict__ q,
                                                        bf16* __restrict__ kv,
                                                        const float* __restrict__ qw,
                                                        const float* __restrict__ kw) {
  const int gw = (blockIdx.x * 256 + threadIdx.x) >> 6;
  const int lane = threadIdx.x & 63;
  bf16* base;
  const float* wgt;
  float post;
  int t;
  if (gw < cT * cH) {
    t = gw >> 5;
    int h = gw & 31;
    base = q + (size_t)t * (cH * cHD) + h * cHD;
    wgt = qw;
    post = SCALE;
  } else {
    int g2 = gw - cT * cH;
    t = g2 >> 3;
    int h = g2 & 7;
    base = kv + (size_t)t * (2 * cKV * cHD) + h * cHD;  // k part of kv buffer
    wgt = kw;
    post = 1.0f;
  }
  const int d0 = lane * 2;
  float x0 = (float)base[d0], x1 = (float)base[d0 + 1];
  float ss = x0 * x0 + x1 * x1;
#pragma unroll
  for (int off = 32; off > 0; off >>= 1) ss += __shfl_xor(ss, off, 64);
  const float rs = rsqrtf(ss * (1.0f / 128.0f) + 1e-6f);
  float y0 = x0 * rs * wgt[d0];
  float y1 = x1 * rs * wgt[d0 + 1];
  float p0 = __shfl_xor(y0, 32, 64);
  float p1 = __shfl_xor(y1, 32, 64);
  const float sgn = (lane < 32) ? -1.0f : 1.0f;  // first half gets -x2
  const int fi = d0 & 63;
  const float c1 = -19.93156856932417f / 64.0f;  // -log2(1e6)/64
  float inv0 = exp2f((float)fi * c1);
  float inv1 = exp2f((float)(fi + 1) * c1);
  float a0 = (float)t * inv0, a1 = (float)t * inv1;
  float o0 = (y0 * cosf(a0) + sgn * p0 * sinf(a0)) * post;
  float o1 = (y1 * cosf(a1) + sgn * p1 * sinf(a1)) * post;
  base[d0] = (bf16)o0;
  base[d0 + 1] = (bf16)o1;
}

// ---------------------------------------------------------------------------
// Score upper bound: S <= 128*SCALE*max|qw|*max|kw| (RMSNorm bounds row norms,
// RoPE is a rotation). Used as the fixed softmax shift C (shift-invariant).
// ---------------------------------------------------------------------------
__global__ void bound_kernel(const float* __restrict__ qw,
                             const float* __restrict__ kw,
                             float* __restrict__ cb) {
  const int lane = threadIdx.x;  // 64 threads
  float mq = fmaxf(fabsf(qw[lane]), fabsf(qw[lane + 64]));
  float mk = fmaxf(fabsf(kw[lane]), fabsf(kw[lane + 64]));
#pragma unroll
  for (int off = 32; off > 0; off >>= 1) {
    mq = fmaxf(mq, __shfl_xor(mq, off, 64));
    mk = fmaxf(mk, __shfl_xor(mk, off, 64));
  }
  if (lane == 0) *cb = 128.0f * SCALE * mq * mk + 1e-3f;
}

// ---------------------------------------------------------------------------
// MFMA flash attention (causal, GQA), fixed-C softmax (no per-tile cross-lane
// reductions, no rescaling). 128 Q rows per block, 4 waves, wave = 32 rows.
// Each Ks/VT B-frag read feeds 2 MFMAs (mt=0,1). Longest blocks launch first.
// LDS = 54272 B -> 3 blocks/CU.
// ---------------------------------------------------------------------------
__global__ __launch_bounds__(256) void flash_kernel(const bf16* __restrict__ q,
                                                    const bf16* __restrict__ kv,
                                                    const float* __restrict__ cb,
                                                    bf16* __restrict__ out) {
  __shared__ bf16 Ks[64][136];
  __shared__ bf16 VT[128][72];
  __shared__ bf16 Ps[4][32][72];

  constexpr int KVS = 2 * cKV * cHD;  // 2048, kv row stride
  const int qt = gridDim.x - 1 - blockIdx.x;  // descending work order
  const int h = blockIdx.y;
  const int qm0 = qt * 128;
  const int kh = h >> 2;  // kv head (G=4)
  const int tid = threadIdx.x;
  const int lane = tid & 63, w = tid >> 6;
  const int ln = lane & 15, kg = lane >> 4;
  const float C = *cb;
  const int row0 = qm0 + w * 32;  // wave's first Q row

  // --- preload Q A-frags: rows row0 + mt*16 + ln ---
  bf16x8 qa[2][4];
#pragma unroll
  for (int mt = 0; mt < 2; ++mt) {
    const bf16* qrow =
        q + (size_t)(row0 + mt * 16 + ln) * (cH * cHD) + h * cHD + kg * 8;
#pragma unroll
    for (int kk = 0; kk < 4; ++kk) qa[mt][kk] = *(const bf16x8*)(qrow + kk * 32);
  }

  const int sl = tid >> 2, sc = tid & 3;    // K staging: row sl, chunk sc*32
  const int vp = tid & 31, vc = tid >> 5;   // V staging: row-pair 2vp, chunk vc*16

  float l_r[2][4] = {};
  f32x4 o_acc[2][8] = {};

  const int nkt = 2 * qt + 2;
  for (int kt = 0; kt < nkt; ++kt) {
    // ---- stage K tile ----
    {
      const bf16* krow = kv + (size_t)(kt * 64 + sl) * KVS + kh * cHD + sc * 32;
#pragma unroll
      for (int i = 0; i < 4; ++i)
        *(bf16x8*)(&Ks[sl][sc * 32 + i * 8]) = *(const bf16x8*)(krow + i * 8);
    }
    // ---- stage V tile transposed (pair-packed b32 writes) ----
    {
      const bf16* vrow =
          kv + cKV * cHD + (size_t)(kt * 64 + 2 * vp) * KVS + kh * cHD + vc * 16;
      bf16x8 a0 = *(const bf16x8*)(vrow);
      bf16x8 a1 = *(const bf16x8*)(vrow + 8);
      bf16x8 b0 = *(const bf16x8*)(vrow + KVS);
      bf16x8 b1 = *(const bf16x8*)(vrow + KVS + 8);
#pragma unroll
      for (int i = 0; i < 8; ++i) {
        union { bf16 hh[2]; unsigned u; } pk;
        pk.hh[0] = a0[i]; pk.hh[1] = b0[i];
        *(unsigned*)(&VT[vc * 16 + i][2 * vp]) = pk.u;
        pk.hh[0] = a1[i]; pk.hh[1] = b1[i];
        *(unsigned*)(&VT[vc * 16 + 8 + i][2 * vp]) = pk.u;
      }
    }
    __syncthreads();

    // ---- S = Q K^T : B-frags shared across mt ----
    f32x4 s_acc[2][4] = {};
#pragma unroll
    for (int kk = 0; kk < 4; ++kk)
#pragma unroll
      for (int nt = 0; nt < 4; ++nt) {
        bf16x8 bfr = *(const bf16x8*)(&Ks[nt * 16 + ln][kk * 32 + kg * 8]);
        s_acc[0][nt] = __builtin_amdgcn_mfma_f32_16x16x32_bf16(
            qa[0][kk], bfr, s_acc[0][nt], 0, 0, 0);
        s_acc[1][nt] = __builtin_amdgcn_mfma_f32_16x16x32_bf16(
            qa[1][kk], bfr, s_acc[1][nt], 0, 0, 0);
      }

    // ---- P = exp(S - C) (masked on edge tiles), per-lane row sums ----
    const bool edge = (kt * 64 + 63 > row0);  // wave-uniform
#pragma unroll
    for (int mt = 0; mt < 2; ++mt)
#pragma unroll
      for (int nt = 0; nt < 4; ++nt)
#pragma unroll
        for (int r = 0; r < 4; ++r) {
          float pe = __expf(s_acc[mt][nt][r] - C);
          if (edge) {
            int col = kt * 64 + nt * 16 + ln;
            int row = row0 + mt * 16 + kg * 4 + r;
            if (col > row) pe = 0.f;
          }
          l_r[mt][r] += pe;
          Ps[w][mt * 16 + kg * 4 + r][nt * 16 + ln] = (bf16)pe;
        }

    // ---- O += P V (no rescale needed with fixed C) ----
#pragma unroll
    for (int kk2 = 0; kk2 < 2; ++kk2) {
      bf16x8 pa0 = *(const bf16x8*)(&Ps[w][ln][kk2 * 32 + kg * 8]);
      bf16x8 pa1 = *(const bf16x8*)(&Ps[w][16 + ln][kk2 * 32 + kg * 8]);
#pragma unroll
      for (int dt = 0; dt < 8; ++dt) {
        bf16x8 vb = *(const bf16x8*)(&VT[dt * 16 + ln][kk2 * 32 + kg * 8]);
        o_acc[0][dt] = __builtin_amdgcn_mfma_f32_16x16x32_bf16(
            pa0, vb, o_acc[0][dt], 0, 0, 0);
        o_acc[1][dt] = __builtin_amdgcn_mfma_f32_16x16x32_bf16(
            pa1, vb, o_acc[1][dt], 0, 0, 0);
      }
    }
    __syncthreads();
  }

  // ---- one final cross-lane reduction of l over ln (within kg group) ----
#pragma unroll
  for (int mt = 0; mt < 2; ++mt)
#pragma unroll
    for (int r = 0; r < 4; ++r) {
      float l = l_r[mt][r];
#pragma unroll
      for (int off = 1; off <= 8; off <<= 1) l += __shfl_xor(l, off, 64);
      l_r[mt][r] = 1.0f / l;
    }

  // ---- epilogue ----
#pragma unroll
  for (int mt = 0; mt < 2; ++mt) {
    bf16* op = out + (size_t)(row0 + mt * 16 + kg * 4) * (cH * cHD) + h * cHD + ln;
#pragma unroll
    for (int dt = 0; dt < 8; ++dt)
#pragma unroll
      for (int r = 0; r < 4; ++r)
        op[(size_t)r * (cH * cHD) + dt * 16] = (bf16)(o_acc[mt][dt][r] * l_r[mt][r]);
  }
}

// ---------------------------------------------------------------------------
// Workspace choreography (peak exactly 64 MiB, stream-ordered reuse):
//   [ 0,16M): xb (x bf16)            -> attn (after kv-gemm done)
//   [16,48M): WqT (32M)              -> { WkvT [16,32M), kv [32,40M), Cb@46M }
//                                    -> WoT (after flash)
//   [48,64M): q bf16
// ---------------------------------------------------------------------------
extern "C" void kernel_launch(void* const* d_in, const int* in_sizes, int n_in,
                              void* d_out, int out_size, void* d_ws, size_t ws_size,
                              hipStream_t stream) {
  const float* x  = (const float*)d_in[0];
  const float* Wq = (const float*)d_in[1];
  const float* Wk = (const float*)d_in[2];
  const float* Wv = (const float*)d_in[3];
  const float* Wo = (const float*)d_in[4];
  const float* qw = (const float*)d_in[5];
  const float* kw = (const float*)d_in[6];
  float* out = (float*)d_out;

  char* ws = (char*)d_ws;
  bf16* xb   = (bf16*)ws;
  bf16* WqT  = (bf16*)(ws + (16u << 20));
  bf16* WkvT = (bf16*)(ws + (16u << 20));
  bf16* kvb  = (bf16*)(ws + (32u << 20));
  float* cb  = (float*)(ws + (46u << 20));
  bf16* qb   = (bf16*)(ws + (48u << 20));
  bf16* attn = (bf16*)ws;
  bf16* WoT  = (bf16*)(ws + (16u << 20));

  // x -> bf16
  convert_kernel<<<(cT * cD) / (8 * 256), 256, 0, stream>>>(x, xb);
  // Wq^T bf16; q = xb * WqT^T (bf16 out)
  convT_kernel<<<dim3(cD / 64, cD / 64), 256, 0, stream>>>(Wq, WqT, cD, cD);
  gemm_bt_kernel<128, bf16><<<dim3(cD / 128, cT / 128), 256, 0, stream>>>(
      xb, WqT, qb, cT, cD, cD);
  // Wk^T|Wv^T bf16 (fused 2048x4096); kv = xb * WkvT^T (bf16 out)
  convT_kernel<<<dim3((cKV * cHD) / 64, cD / 64), 256, 0, stream>>>(Wk, WkvT, cD, cKV * cHD);
  convT_kernel<<<dim3((cKV * cHD) / 64, cD / 64), 256, 0, stream>>>(
      Wv, WkvT + (size_t)(cKV * cHD) * cD, cD, cKV * cHD);
  gemm_bt_kernel<64, bf16><<<dim3((2 * cKV * cHD) / 64, cT / 128), 256, 0, stream>>>(
      xb, WkvT, kvb, cT, 2 * cKV * cHD, cD);
  // rmsnorm + rope (in place, bf16); softmax shift bound
  norm_rope_kernel<<<(cT * (cH + cKV)) / 4, 256, 0, stream>>>(qb, kvb, qw, kw);
  bound_kernel<<<1, 64, 0, stream>>>(qw, kw, cb);
  // flash attention -> attn bf16 (reuses xb region)
  flash_kernel<<<dim3(cT / 128, cH), 256, 0, stream>>>(qb, kvb, cb, attn);
  // Wo^T bf16 (overwrites WkvT/kv region - both dead); out = attn * WoT^T (fp32)
  convT_kernel<<<dim3(cD / 64, cD / 64), 256, 0, stream>>>(Wo, WoT, cD, cD);
  gemm_bt_kernel<128, float><<<dim3(cD / 128, cT / 128), 256, 0, stream>>>(
      attn, WoT, out, cT, cD, cD);
}